// Round 4
// baseline (220.175 us; speedup 1.0000x reference)
//
#include <hip/hip_runtime.h>

// PositionalEncoding: out[b,s,i] = x[b,s,i] + pe[s,i]
//   pe[s,i] = sin(s / 10000^((i/2)/D)) if i even, cos(...) if i odd
// B=8, S=4096, D=1024, fp32.
//
// R7: R6 (branch-free HW sin/cos) with cache policy fixed:
//   - x loads TEMPORAL: x (134 MB) fits in the 256 MB Infinity Cache and
//     is re-read every bench iteration. R1 counters proved 50% L3
//     residency with plain loads (FETCH 64 MB for a 134 MB read). R6's
//     nontemporal load marked x evict-first and threw that away.
//   - out stores NONTEMPORAL: streamed, never re-read, must not evict x.
// History: batch-amortized @16MB stride = TLB-thrash (2.2 TB/s), dead.
// table+add = 3-stream, slower than fused. libm sincosf = divergent
// Payne-Hanek path, replaced by revolutions-domain v_sin/v_cos (R6).
// Compute budget ~78 SIMD-cyc/wave vs ~800-cyc memory budget -> firmly
// memory-bound; remaining lever is HBM traffic via L3 residency.

#define PE_B 8
#define PE_S 4096
#define PE_D 1024
#define ROW4 (PE_S * PE_D / 4)          // float4s per batch = 1,048,576

typedef float v4f __attribute__((ext_vector_type(4)));

__global__ __launch_bounds__(256) void pe_fused_hwsin(
    const float* __restrict__ x, float* __restrict__ out) {
    const int idx = blockIdx.x * blockDim.x + threadIdx.x;   // 0 .. B*ROW4-1
    const int r   = idx & (ROW4 - 1);
    const int i   = (r & (PE_D / 4 - 1)) * 4;                // elem index in row
    const int s   = r >> 8;                                  // D/4 = 256

    const v4f v = *(const v4f*)(x + (size_t)idx * 4);        // temporal: keep in L3

    // rev = pos * 10000^(-k/D) / (2*pi)   (angle in revolutions)
    const float pos = (float)s;
    const float c   = -0.012976281620653759f;   // -log2(10000)/1024
    const float L   = -2.6514961294723187f;     // -log2(2*pi)
    const float k0  = (float)(i >> 1);
    const float w0  = __builtin_amdgcn_exp2f(fmaf(k0,        c, L));
    const float w1  = __builtin_amdgcn_exp2f(fmaf(k0 + 1.0f, c, L));
    // range-reduce to [-0.5, 0.5] revolutions; fma gives single-rounding fract
    const float f0  = fmaf(pos, w0, -rintf(pos * w0));
    const float f1  = fmaf(pos, w1, -rintf(pos * w1));
    const v4f pe = { __builtin_amdgcn_sinf(f0), __builtin_amdgcn_cosf(f0),
                     __builtin_amdgcn_sinf(f1), __builtin_amdgcn_cosf(f1) };

    __builtin_nontemporal_store(v + pe, (v4f*)(out + (size_t)idx * 4));
}

extern "C" void kernel_launch(void* const* d_in, const int* in_sizes, int n_in,
                              void* d_out, int out_size, void* d_ws, size_t ws_size,
                              hipStream_t stream) {
    const float* x = (const float*)d_in[0];
    float* out = (float*)d_out;
    (void)d_ws; (void)ws_size;
    const int n4 = PE_B * ROW4;                       // 8,388,608 float4s
    pe_fused_hwsin<<<n4 / 256, 256, 0, stream>>>(x, out);
}

// Round 5
// 216.683 us; speedup vs baseline: 1.0161x; 1.0161x over previous
//
#include <hip/hip_runtime.h>

// PositionalEncoding: out[b,s,i] = x[b,s,i] + pe[s,i]
//   pe[s,i] = sin(s / 10000^((i/2)/D)) if i even, cos(...) if i odd
// B=8, S=4096, D=1024, fp32.
//
// R8: R6 config with ONE variable flipped: store is PLAIN (was nt).
// Evidence trail:
//  - R4/R7: temporal x-load regressed vs nt (220.2 vs 216.3). The 512MB
//    harness poison fill sweeps the 256MB L3 every iteration -> no x
//    residency is possible. All 268 MB is mandatory HBM traffic.
//  - nt LOAD proven good (A/B vs temporal). nt STORE never isolated.
//    The in-situ fills hit 6.7 TB/s write-only with PLAIN stores (L2
//    write-back absorbs bursts, drains at HBM rate); nt stores bypass
//    L2 and may throttle the MC. Est. kernel 68 us = 3.9 TB/s vs 6.3
//    copy ceiling -> testing store policy as the remaining lever.
//  - MLP not the limit (32 waves/CU x 1KB in flight >> BW*latency);
//    trig not the limit (~48 trans-cyc/wave vs ~200-cyc memory budget).
// pe math: revolutions-domain v_sin/v_cos (branch-free), absmax 0.03125.

#define PE_B 8
#define PE_S 4096
#define PE_D 1024
#define ROW4 (PE_S * PE_D / 4)          // float4s per batch = 1,048,576

typedef float v4f __attribute__((ext_vector_type(4)));

__global__ __launch_bounds__(256) void pe_fused_hwsin(
    const float* __restrict__ x, float* __restrict__ out) {
    const int idx = blockIdx.x * blockDim.x + threadIdx.x;   // 0 .. B*ROW4-1
    const int r   = idx & (ROW4 - 1);
    const int i   = (r & (PE_D / 4 - 1)) * 4;                // elem index in row
    const int s   = r >> 8;                                  // D/4 = 256

    const v4f v = __builtin_nontemporal_load((const v4f*)(x + (size_t)idx * 4));

    // rev = pos * 10000^(-k/D) / (2*pi)   (angle in revolutions)
    const float pos = (float)s;
    const float c   = -0.012976281620653759f;   // -log2(10000)/1024
    const float L   = -2.6514961294723187f;     // -log2(2*pi)
    const float k0  = (float)(i >> 1);
    const float w0  = __builtin_amdgcn_exp2f(fmaf(k0,        c, L));
    const float w1  = __builtin_amdgcn_exp2f(fmaf(k0 + 1.0f, c, L));
    // range-reduce to [-0.5, 0.5] revolutions; fma gives single-rounding fract
    const float f0  = fmaf(pos, w0, -rintf(pos * w0));
    const float f1  = fmaf(pos, w1, -rintf(pos * w1));
    const v4f pe = { __builtin_amdgcn_sinf(f0), __builtin_amdgcn_cosf(f0),
                     __builtin_amdgcn_sinf(f1), __builtin_amdgcn_cosf(f1) };

    *(v4f*)(out + (size_t)idx * 4) = v + pe;    // PLAIN store (L2 write-back)
}

extern "C" void kernel_launch(void* const* d_in, const int* in_sizes, int n_in,
                              void* d_out, int out_size, void* d_ws, size_t ws_size,
                              hipStream_t stream) {
    const float* x = (const float*)d_in[0];
    float* out = (float*)d_out;
    (void)d_ws; (void)ws_size;
    const int n4 = PE_B * ROW4;                       // 8,388,608 float4s
    pe_fused_hwsin<<<n4 / 256, 256, 0, stream>>>(x, out);
}